// Round 1
// 452.421 us; speedup vs baseline: 1.1262x; 1.1262x over previous
//
#include <hip/hip_runtime.h>
#include <cstdint>
#include <cstddef>

typedef __bf16 bf16;
typedef __bf16 bf16x8 __attribute__((ext_vector_type(8)));
typedef float f32x4 __attribute__((ext_vector_type(4)));

#define BDIM 4
#define TDIM 2048
#define DDIM 2048
#define HDIM 8
#define DHD 256
#define MTOT 8192
#define NCHUNK 64
#define LCHUNK 32

// async 16B global->LDS; LDS dest = wave-uniform base + lane*16
__device__ __forceinline__ void stage16(const bf16* g, bf16* l) {
  __builtin_amdgcn_global_load_lds(
      (const __attribute__((address_space(1))) void*)g,
      (__attribute__((address_space(3))) void*)l, 16, 0, 0);
}

// raw barrier / counted vmcnt with compiler memory fences (no auto vmcnt(0) drain)
#define SBAR() asm volatile("s_barrier" ::: "memory")
#define WAITVM(N) asm volatile("s_waitcnt vmcnt(" #N ")" ::: "memory")

__device__ __forceinline__ float sigmoid_f(float x) {
  return __fdividef(1.f, 1.f + __expf(-x));
}
__device__ __forceinline__ float gelu_tanh(float v) {
  float u = 0.7978845608028654f * (v + 0.044715f * v * v * v);
  u = fminf(fmaxf(u, -15.f), 15.f);
  float t = __expf(2.f * u);                       // tanh(u) = (t-1)/(t+1)
  return 0.5f * v * (1.f + __fdividef(t - 1.f, t + 1.f));
}
__device__ __forceinline__ float softplus_f(float x) {
  return __logf(1.f + __expf(x));                  // x in [-1.2, 0.4] here
}

// ---------------------------------------------------------------------------
// fp32 -> bf16 bulk convert, 8 elem/thread (count must be /2048)
// ---------------------------------------------------------------------------
__global__ __launch_bounds__(256) void f2b(const float* __restrict__ src,
                                           bf16* __restrict__ dst) {
  size_t i = ((size_t)blockIdx.x * 256 + threadIdx.x) * 8;
  const float4 a = *(const float4*)(src + i);
  const float4 b = *(const float4*)(src + i + 4);
  bf16x8 r;
  r[0] = (bf16)a.x; r[1] = (bf16)a.y; r[2] = (bf16)a.z; r[3] = (bf16)a.w;
  r[4] = (bf16)b.x; r[5] = (bf16)b.y; r[6] = (bf16)b.z; r[7] = (bf16)b.w;
  *(bf16x8*)(dst + i) = r;
}

// ---------------------------------------------------------------------------
// C[m,n] = epi(sum_k A[m,k]*B[n,k] + bias[n]); bf16 operands, fp32 accum.
// 256x256 tile, BK=64, 8 waves (2M x 4N), double-buffered XOR-swizzled LDS,
// counted vmcnt(8) one-K-tile-deep async prefetch (never drains in-loop).
// Requires M%256==0, N%256==0, K%64==0, K/64>=2.
// LDS layout: sX[p][row][64]; 16B slot s of row r holds global k-chunk s^(r&7).
// ---------------------------------------------------------------------------
template <typename TO, int EPI>
__global__ __launch_bounds__(512, 2) void gemm256(
    const bf16* __restrict__ A, const bf16* __restrict__ Bm,
    const float* __restrict__ bias, TO* __restrict__ C,
    int K, int lda, int ldb, int ldc) {
  const int n0 = blockIdx.x * 256;
  const int m0 = blockIdx.y * 256;
  __shared__ bf16 sA[2][256][64];   // 64 KiB
  __shared__ bf16 sB[2][256][64];   // 64 KiB
  const int tid = threadIdx.x;
  const int lane = tid & 63;
  const int wid = tid >> 6;         // 0..7
  const int wr = wid >> 2;          // M-half of tile (0..1) -> 128 rows
  const int wc = wid & 3;           // N-quarter (0..3)      -> 64 cols
  const int quad = lane >> 4;
  const int l15 = lane & 15;

  // staging: thread covers row (c*64 + tid>>3), swizzled 16B slot (tid&7)^(row&7)
  const int sr = tid >> 3;                        // 0..63
  const int ks8 = ((tid & 7) ^ (sr & 7)) << 3;    // element offset in 64-wide row
  const bf16* Ag = A + (size_t)(m0 + sr) * lda + ks8;
  const bf16* Bg = Bm + (size_t)(n0 + sr) * ldb + ks8;

  // read-side swizzle: slot (kk*4+quad) ^ (row&7); row&7 == l15&7 for all frags
  const int swz0 = ((quad) ^ (l15 & 7)) << 3;
  const int swz1 = ((4 + quad) ^ (l15 & 7)) << 3;

  f32x4 acc[8][4];
#pragma unroll
  for (int i = 0; i < 8; ++i)
#pragma unroll
    for (int j = 0; j < 4; ++j)
#pragma unroll
      for (int r = 0; r < 4; ++r) acc[i][j][r] = 0.f;

  const int NT = K >> 6;

  // stage one full K-tile (A+B, 256 rows x 64 k each) = 8 loads per wave
  auto STAGE = [&](int p, int tk) {
    const size_t ko = (size_t)tk << 6;
#pragma unroll
    for (int c = 0; c < 4; ++c) {
      stage16(Ag + (size_t)(c * 64) * lda + ko, &sA[p][c * 64 + wid * 8][0]);
      stage16(Bg + (size_t)(c * 64) * ldb + ko, &sB[p][c * 64 + wid * 8][0]);
    }
  };

  STAGE(0, 0);
  STAGE(1, 1);
  WAITVM(8);     // tile 0 landed; tile 1's 8 loads still in flight
  SBAR();

  int p = 0;
  for (int t = 0; t < NT; ++t) {
    const bf16* As0 = &sA[p][0][0];
    const bf16* Bs0 = &sB[p][0][0];
#pragma unroll
    for (int mh = 0; mh < 2; ++mh) {
      bf16x8 afr[4][2];
#pragma unroll
      for (int mi = 0; mi < 4; ++mi) {
        const int arow = wr * 128 + mh * 64 + mi * 16 + l15;
        afr[mi][0] = *(const bf16x8*)(As0 + arow * 64 + swz0);
        afr[mi][1] = *(const bf16x8*)(As0 + arow * 64 + swz1);
      }
#pragma unroll
      for (int nh = 0; nh < 2; ++nh) {
        bf16x8 bfr[2][2];
#pragma unroll
        for (int ni = 0; ni < 2; ++ni) {
          const int brow = wc * 64 + nh * 32 + ni * 16 + l15;
          bfr[ni][0] = *(const bf16x8*)(Bs0 + brow * 64 + swz0);
          bfr[ni][1] = *(const bf16x8*)(Bs0 + brow * 64 + swz1);
        }
        __builtin_amdgcn_s_setprio(1);
#pragma unroll
        for (int mi = 0; mi < 4; ++mi)
#pragma unroll
          for (int ni = 0; ni < 2; ++ni) {
            acc[mh * 4 + mi][nh * 2 + ni] = __builtin_amdgcn_mfma_f32_16x16x32_bf16(
                afr[mi][0], bfr[ni][0], acc[mh * 4 + mi][nh * 2 + ni], 0, 0, 0);
            acc[mh * 4 + mi][nh * 2 + ni] = __builtin_amdgcn_mfma_f32_16x16x32_bf16(
                afr[mi][1], bfr[ni][1], acc[mh * 4 + mi][nh * 2 + ni], 0, 0, 0);
          }
        __builtin_amdgcn_s_setprio(0);
      }
    }
    // all waves' ds_reads of buf[p] completed (consumed by MFMAs above)
    SBAR();
    if (t + 2 < NT) {
      STAGE(p, t + 2);   // overwrite just-freed buffer; lands >= next barrier
      WAITVM(8);         // tile t+1's loads landed; t+2's 8 stay in flight
    } else {
      WAITVM(0);         // tail: drain remaining (t+1) loads
    }
    SBAR();
    p ^= 1;
  }

#pragma unroll
  for (int nn = 0; nn < 4; ++nn) {
    const int n = n0 + wc * 64 + nn * 16 + l15;
    const float bv = bias[n];
#pragma unroll
    for (int mm = 0; mm < 8; ++mm) {
#pragma unroll
      for (int r = 0; r < 4; ++r) {
        const int m = m0 + wr * 128 + mm * 16 + quad * 4 + r;
        float v = acc[mm][nn][r] + bv;
        if (EPI == 1) v = gelu_tanh(v);
        C[(size_t)m * ldc + n] = (TO)v;
      }
    }
  }
}

// ---------------------------------------------------------------------------
// gate pre-activation GEMM: one gate per block (z = h*2+g), 128x128 tile,
// K = DH = 256. out[m, h*DHD + n] = sum_k xconv[m, h*DHD+k] * W[g][h][n][k]
// ---------------------------------------------------------------------------
__global__ __launch_bounds__(256) void gate_gemm(
    const bf16* __restrict__ xconv,
    const bf16* __restrict__ gxT, const bf16* __restrict__ gaT,
    bf16* __restrict__ gxr, bf16* __restrict__ gar) {
  const int h = blockIdx.z >> 1;
  const int g = blockIdx.z & 1;
  const bf16* A = xconv + h * DHD;                       // lda = DDIM
  const bf16* Bm = (g ? gaT : gxT) + (size_t)h * DHD * DHD;  // ldb = DHD
  bf16* C = (g ? gar : gxr) + h * DHD;                   // ldc = DDIM
  const int n0 = blockIdx.x * 128;
  const int m0 = blockIdx.y * 128;
  __shared__ bf16 As[128 * 32];
  __shared__ bf16 Bs[128 * 32];
  const int tid = threadIdx.x;
  const int lane = tid & 63;
  const int wid = tid >> 6;
  const int waveM = wid >> 1, waveN = wid & 1;
  const int quad = lane >> 4;
  const int l15 = lane & 15;
  const int srow = lane >> 2;
  const int scol = (lane & 3) * 8;

  f32x4 acc[4][4];
#pragma unroll
  for (int i = 0; i < 4; ++i)
#pragma unroll
    for (int j = 0; j < 4; ++j)
#pragma unroll
      for (int r = 0; r < 4; ++r) acc[i][j][r] = 0.f;

  for (int k0 = 0; k0 < DHD; k0 += 32) {
    if (k0) __syncthreads();
#pragma unroll
    for (int cc = 0; cc < 2; ++cc) {
      const int q = wid * 2 + cc;
      const int row = q * 16 + srow;
      stage16(A + (size_t)(m0 + row) * DDIM + k0 + scol, As + q * 512);
      stage16(Bm + (size_t)(n0 + row) * DHD + k0 + scol, Bs + q * 512);
    }
    __syncthreads();
    bf16x8 af[4], bfr[4];
#pragma unroll
    for (int i = 0; i < 4; ++i) {
      af[i]  = *(const bf16x8*)&As[(waveM * 64 + i * 16 + l15) * 32 + quad * 8];
      bfr[i] = *(const bf16x8*)&Bs[(waveN * 64 + i * 16 + l15) * 32 + quad * 8];
    }
#pragma unroll
    for (int i = 0; i < 4; ++i)
#pragma unroll
      for (int j = 0; j < 4; ++j)
        acc[i][j] = __builtin_amdgcn_mfma_f32_16x16x32_bf16(af[i], bfr[j], acc[i][j], 0, 0, 0);
  }

#pragma unroll
  for (int j = 0; j < 4; ++j) {
    const int n = n0 + waveN * 64 + j * 16 + l15;
#pragma unroll
    for (int i = 0; i < 4; ++i) {
#pragma unroll
      for (int r = 0; r < 4; ++r) {
        const int m = m0 + waveM * 64 + i * 16 + quad * 4 + r;
        C[(size_t)m * DDIM + n] = (bf16)acc[i][j][r];
      }
    }
  }
}

// ---------------------------------------------------------------------------
// depthwise causal conv, TW=4; bf16 data, fp32 weights
// ---------------------------------------------------------------------------
__global__ __launch_bounds__(256) void conv_kernel(
    const bf16* __restrict__ xp, const float* __restrict__ cw,
    const float* __restrict__ cb, const int* __restrict__ segp,
    bf16* __restrict__ xc) {
  int v = blockIdx.x * 256 + threadIdx.x;
  int dv = v & (DDIM / 8 - 1);
  int m = v >> 8;
  int d0 = dv * 8;
  int t = m & (TDIM - 1);
  int sp = segp[m];
  float acc[8];
#pragma unroll
  for (int j = 0; j < 8; ++j) acc[j] = cb[d0 + j];
#pragma unroll
  for (int i = 0; i < 4; ++i) {
    int shift = 3 - i;
    if (t >= shift && sp >= shift) {
      bf16x8 xv = *(const bf16x8*)&xp[(size_t)(m - shift) * DDIM + d0];
#pragma unroll
      for (int j = 0; j < 8; ++j) acc[j] = fmaf((float)xv[j], cw[i * DDIM + d0 + j], acc[j]);
    }
  }
  bf16x8 o;
#pragma unroll
  for (int j = 0; j < 8; ++j) o[j] = (bf16)acc[j];
  *(bf16x8*)&xc[(size_t)m * DDIM + d0] = o;
}

// ---------------------------------------------------------------------------
// transpose + convert gate weights: dst[h][j][i] = (bf16)src[h][i][j]
// ---------------------------------------------------------------------------
__global__ __launch_bounds__(256) void transpose_gates(
    const float* __restrict__ gxw, const float* __restrict__ gaw,
    bf16* __restrict__ gxT, bf16* __restrict__ gaT) {
  __shared__ bf16 tile[32][33];
  int zz = blockIdx.z;
  int h = zz >> 1;
  const float* src = (zz & 1) ? gaw : gxw;
  bf16* dst = (zz & 1) ? gaT : gxT;
  int j0 = blockIdx.x * 32;
  int i0 = blockIdx.y * 32;
  int r = threadIdx.x >> 5;
  int c = threadIdx.x & 31;
  for (int rr = r; rr < 32; rr += 8)
    tile[rr][c] = (bf16)src[(size_t)(h * DHD + i0 + rr) * DHD + j0 + c];
  __syncthreads();
  for (int rr = r; rr < 32; rr += 8)
    dst[(size_t)(h * DHD + j0 + rr) * DHD + i0 + c] = tile[c][rr];
}

// ---------------------------------------------------------------------------
// RG-LRU elementwise recompute, shared by scan phases
// ---------------------------------------------------------------------------
__device__ __forceinline__ void lru_elem(float pgx, float pga, float xc,
                                         float spv, bool reset,
                                         float& a, float& nr) {
  const float gx = sigmoid_f(pgx);
  const float ga = sigmoid_f(pga);
  const float la = -8.f * ga * spv;
  a = reset ? 0.f : __expf(la);
  const float mult = reset ? 1.f : sqrtf(fmaxf(1.f - __expf(2.f * la), 0.f));
  nr = xc * gx * mult;
}

// chunked scan phase 1: per (b, chunk, d) compute prod(a) and h across chunk
__global__ __launch_bounds__(256) void scan_phase1(
    const bf16* __restrict__ gxr, const bf16* __restrict__ gar,
    const bf16* __restrict__ xconv,
    const float* __restrict__ gxb, const float* __restrict__ gab,
    const float* __restrict__ apar, const int* __restrict__ segp,
    float* __restrict__ chA, float* __restrict__ chH) {
  int idx = blockIdx.x * 256 + threadIdx.x;
  int d = idx & (DDIM - 1);
  int c = (idx >> 11) & (NCHUNK - 1);
  int b = idx >> 17;
  const float gxbv = gxb[d], gabv = gab[d];
  const float spv = softplus_f(apar[d]);
  const int mrow = b * TDIM + c * LCHUNK;
  size_t base = (size_t)mrow * DDIM + d;
  float A = 1.f, hh = 0.f;
  for (int i = 0; i < LCHUNK; ++i) {
    size_t o = base + (size_t)i * DDIM;
    float a, nr;
    lru_elem((float)gxr[o] + gxbv, (float)gar[o] + gabv, (float)xconv[o],
             spv, segp[mrow + i] == 0, a, nr);
    hh = fmaf(a, hh, nr);
    A *= a;
  }
  int ci = (b * NCHUNK + c) * DDIM + d;
  chA[ci] = A;
  chH[ci] = hh;
}

__global__ __launch_bounds__(256) void scan_phase2(
    const float* __restrict__ chA, const float* __restrict__ chH,
    float* __restrict__ hst) {
  int idx = blockIdx.x * 256 + threadIdx.x;
  int d = idx & (DDIM - 1);
  int b = idx >> 11;
  float s = 0.f;
  for (int c = 0; c < NCHUNK; ++c) {
    int ci = (b * NCHUNK + c) * DDIM + d;
    hst[ci] = s;
    s = fmaf(chA[ci], s, chH[ci]);
  }
}

// phase 3: replay scan with chunk-start state; z = h*y in-place over y
__global__ __launch_bounds__(256) void scan_phase3(
    const bf16* __restrict__ gxr, const bf16* __restrict__ gar,
    const bf16* __restrict__ xconv,
    const float* __restrict__ gxb, const float* __restrict__ gab,
    const float* __restrict__ apar, const int* __restrict__ segp,
    const float* __restrict__ hst, bf16* __restrict__ yz) {
  int idx = blockIdx.x * 256 + threadIdx.x;
  int d = idx & (DDIM - 1);
  int c = (idx >> 11) & (NCHUNK - 1);
  int b = idx >> 17;
  const float gxbv = gxb[d], gabv = gab[d];
  const float spv = softplus_f(apar[d]);
  const int mrow = b * TDIM + c * LCHUNK;
  size_t base = (size_t)mrow * DDIM + d;
  float hh = hst[(b * NCHUNK + c) * DDIM + d];
  for (int i = 0; i < LCHUNK; ++i) {
    size_t o = base + (size_t)i * DDIM;
    float a, nr;
    lru_elem((float)gxr[o] + gxbv, (float)gar[o] + gabv, (float)xconv[o],
             spv, segp[mrow + i] == 0, a, nr);
    hh = fmaf(a, hh, nr);
    yz[o] = (bf16)(hh * (float)yz[o]);
  }
}

// ---------------------------------------------------------------------------
extern "C" void kernel_launch(void* const* d_in, const int* in_sizes, int n_in,
                              void* d_out, int out_size, void* d_ws, size_t ws_size,
                              hipStream_t stream) {
  const float* x    = (const float*)d_in[0];
  const int*   segp = (const int*)d_in[1];
  const float* Wy   = (const float*)d_in[2];
  const float* by   = (const float*)d_in[3];
  const float* Wx   = (const float*)d_in[4];
  const float* bx   = (const float*)d_in[5];
  const float* cw   = (const float*)d_in[6];
  const float* cb   = (const float*)d_in[7];
  const float* gxw  = (const float*)d_in[8];
  const float* gxb  = (const float*)d_in[9];
  const float* gaw  = (const float*)d_in[10];
  const float* gab  = (const float*)d_in[11];
  const float* apar = (const float*)d_in[12];
  const float* Wout = (const float*)d_in[13];
  const float* bout = (const float*)d_in[14];

  const size_t MD = (size_t)MTOT * DDIM;       // 16.78M elements
  const size_t WD = (size_t)DDIM * DDIM;       // 4.19M elements
  // d_out (fp32, 67 MB) as bf16 scratch until the final GEMM:
  bf16* xb    = (bf16*)d_out;                   // lower: xb -> xconv
  bf16* xproj = (bf16*)((char*)d_out + MD * 2); // upper: xproj -> gxr
  bf16* xconv = xb;
  bf16* gxr   = xproj;

  // ws (~92 MB): gar | W1 | WB1 | WB2 | gxT | gaT | chA | chH | hst
  char* ws = (char*)d_ws;
  bf16*  gar = (bf16*)ws;                        // 33.5 MB
  bf16*  W1  = (bf16*)(ws + MD * 2);             // y -> z (33.5 MB)
  bf16*  WB1 = (bf16*)(ws + 2 * MD * 2);         // Wxb, later Woutb (8.4 MB)
  bf16*  WB2 = (bf16*)(ws + 2 * MD * 2 + WD * 2);// Wyb (8.4 MB)
  char*  tail = ws + 2 * MD * 2 + 2 * WD * 2;
  const size_t GW = (size_t)HDIM * DHD * DHD * 2;      // 1 MiB
  const size_t CH = (size_t)BDIM * NCHUNK * DDIM * 4;  // 2 MiB
  bf16*  gxT = (bf16*)tail;
  bf16*  gaT = (bf16*)(tail + GW);
  float* chA = (float*)(tail + 2 * GW);
  float* chH = (float*)(tail + 2 * GW + CH);
  float* hst = (float*)(tail + 2 * GW + 2 * CH);

  dim3 blk(256);
  f2b<<<dim3(MD / 2048), blk, 0, stream>>>(x, xb);
  f2b<<<dim3(WD / 2048), blk, 0, stream>>>(Wx, WB1);
  f2b<<<dim3(WD / 2048), blk, 0, stream>>>(Wy, WB2);
  transpose_gates<<<dim3(8, 8, 16), blk, 0, stream>>>(gxw, gaw, gxT, gaT);

  // xproj = x @ Wx^T + bx ; y = gelu(x @ Wy^T + by)   (256^2 deep-pipelined)
  gemm256<bf16, 0><<<dim3(8, 32), dim3(512), 0, stream>>>(xb, WB1, bx, xproj, DDIM, DDIM, DDIM, DDIM);
  gemm256<bf16, 1><<<dim3(8, 32), dim3(512), 0, stream>>>(xb, WB2, by, W1, DDIM, DDIM, DDIM, DDIM);

  // xconv in-place over xb (reads xproj; xb dead after the two GEMMs)
  conv_kernel<<<dim3(MTOT * (DDIM / 8) / 256), blk, 0, stream>>>(xproj, cw, cb, segp, xconv);

  // gate pre-activations: gxr over xproj (dead), gar in ws
  gate_gemm<<<dim3(2, 64, 16), blk, 0, stream>>>(xconv, gxT, gaT, gxr, gar);

  // chunked scan with fused RG-LRU elementwise; phase3 writes z = h*y over y
  scan_phase1<<<dim3(BDIM * NCHUNK * DDIM / 256), blk, 0, stream>>>(
      gxr, gar, xconv, gxb, gab, apar, segp, chA, chH);
  scan_phase2<<<dim3(BDIM * DDIM / 256), blk, 0, stream>>>(chA, chH, hst);
  scan_phase3<<<dim3(BDIM * NCHUNK * DDIM / 256), blk, 0, stream>>>(
      gxr, gar, xconv, gxb, gab, apar, segp, hst, W1);

  // out = z @ Wout^T + bout (fp32 over all of d_out; scratch dead)
  f2b<<<dim3(WD / 2048), blk, 0, stream>>>(Wout, WB1);
  gemm256<float, 0><<<dim3(8, 32), dim3(512), 0, stream>>>(W1, WB1, bout, (float*)d_out, DDIM, DDIM, DDIM, DDIM);
}

// Round 3
// 420.488 us; speedup vs baseline: 1.2117x; 1.0759x over previous
//
#include <hip/hip_runtime.h>
#include <cstdint>
#include <cstddef>

typedef __bf16 bf16;
typedef __bf16 bf16x8 __attribute__((ext_vector_type(8)));
typedef float f32x4 __attribute__((ext_vector_type(4)));

#define BDIM 4
#define TDIM 2048
#define DDIM 2048
#define HDIM 8
#define DHD 256
#define MTOT 8192
#define NCHUNK 64
#define LCHUNK 32

// async 16B global->LDS; LDS dest = wave-uniform base + lane*16
__device__ __forceinline__ void stage16(const bf16* g, bf16* l) {
  __builtin_amdgcn_global_load_lds(
      (const __attribute__((address_space(1))) void*)g,
      (__attribute__((address_space(3))) void*)l, 16, 0, 0);
}

// raw barrier / counted waits with compiler memory fences (no auto vmcnt(0) drain)
#define SBAR() asm volatile("s_barrier" ::: "memory")
#define WAITVM(N) asm volatile("s_waitcnt vmcnt(" #N ")" ::: "memory")
#define LGKM0() asm volatile("s_waitcnt lgkmcnt(0)" ::: "memory")

__device__ __forceinline__ float sigmoid_f(float x) {
  return __fdividef(1.f, 1.f + __expf(-x));
}
__device__ __forceinline__ float gelu_tanh(float v) {
  float u = 0.7978845608028654f * (v + 0.044715f * v * v * v);
  u = fminf(fmaxf(u, -15.f), 15.f);
  float t = __expf(2.f * u);                       // tanh(u) = (t-1)/(t+1)
  return 0.5f * v * (1.f + __fdividef(t - 1.f, t + 1.f));
}
__device__ __forceinline__ float softplus_f(float x) {
  return __logf(1.f + __expf(x));                  // x in [-1.2, 0.4] here
}

// ---------------------------------------------------------------------------
// fp32 -> bf16 bulk convert, 8 elem/thread (count must be /2048)
// ---------------------------------------------------------------------------
__global__ __launch_bounds__(256) void f2b(const float* __restrict__ src,
                                           bf16* __restrict__ dst) {
  size_t i = ((size_t)blockIdx.x * 256 + threadIdx.x) * 8;
  const float4 a = *(const float4*)(src + i);
  const float4 b = *(const float4*)(src + i + 4);
  bf16x8 r;
  r[0] = (bf16)a.x; r[1] = (bf16)a.y; r[2] = (bf16)a.z; r[3] = (bf16)a.w;
  r[4] = (bf16)b.x; r[5] = (bf16)b.y; r[6] = (bf16)b.z; r[7] = (bf16)b.w;
  *(bf16x8*)(dst + i) = r;
}

// ---------------------------------------------------------------------------
// C[m,n] = epi(sum_k A[m,k]*B[n,k] + bias[n]); bf16 operands, fp32 accum.
// 256x256 tile, BK=64, 8 waves (2M x 4N), double-buffered XOR-swizzled LDS.
// 4-phase-per-K-tile schedule:
//   P0: ds_read A-half0 + B-half0 frags        -> SBAR -> MFMA quad(0,0)
//   P1: ds_read A-half1 + B-half1; lgkmcnt(0)  -> SBAR -> MFMA quad(0,1)
//   P2: stage A-halves of tile t+2 (4 loads)           -> MFMA quad(1,0)
//   P3: stage B-halves of tile t+2 (4 loads)           -> MFMA quad(1,1)
// Race-free: ALL reads of buf[p] hw-complete (lgkmcnt(0)+barrier) before any
// stage16 writes buf[p]. vmcnt(8) at tile top = tile t landed, t+1 in flight.
// XCD-chunked block swizzle: 8 blocks sharing an A-panel land on one XCD.
// Requires M%256==0, N%256==0, K%64==0, K/64>=2, gridDim.x*gridDim.y%8==0.
// ---------------------------------------------------------------------------
template <typename TO, int EPI>
__global__ __launch_bounds__(512, 2) void gemm256(
    const bf16* __restrict__ A, const bf16* __restrict__ Bm,
    const float* __restrict__ bias, TO* __restrict__ C,
    int K, int lda, int ldb, int ldc) {
  // XCD-aware bijective swizzle (nwg = gx*gy, nwg%8==0)
  const int gx = gridDim.x, gy = gridDim.y;
  const int nwg = gx * gy;
  const int did = blockIdx.x + gx * blockIdx.y;
  const int cpx = nwg >> 3;                       // chunk per XCD
  const int lid = (did & 7) * cpx + (did >> 3);
  const int n0 = (lid % gx) * 256;
  const int m0 = (lid / gx) * 256;

  __shared__ bf16 sA[2][256][64];   // 64 KiB
  __shared__ bf16 sB[2][256][64];   // 64 KiB
  const int tid = threadIdx.x;
  const int lane = tid & 63;
  const int wid = tid >> 6;         // 0..7
  const int wr = wid >> 2;          // M-half of tile (0..1) -> 128 rows
  const int wc = wid & 3;           // N-quarter (0..3)      -> 64 cols
  const int quad = lane >> 4;
  const int l15 = lane & 15;

  // staging: thread covers row (c*64 + tid>>3), swizzled 16B slot (tid&7)^(row&7)
  const int sr = tid >> 3;                        // 0..63
  const int ks8 = ((tid & 7) ^ (sr & 7)) << 3;    // element offset in 64-wide row
  const bf16* Ag = A + (size_t)(m0 + sr) * lda + ks8;
  const bf16* Bg = Bm + (size_t)(n0 + sr) * ldb + ks8;

  // read-side swizzle: slot (kk*4+quad) ^ (row&7); row&7 == l15&7 for all frags
  const int swz0 = ((quad) ^ (l15 & 7)) << 3;
  const int swz1 = ((4 + quad) ^ (l15 & 7)) << 3;

  f32x4 acc[8][4];
#pragma unroll
  for (int i = 0; i < 8; ++i)
#pragma unroll
    for (int j = 0; j < 4; ++j)
#pragma unroll
      for (int r = 0; r < 4; ++r) acc[i][j][r] = 0.f;

  const int NT = K >> 6;

#define STAGE_A(P, TK)                                                        \
  do {                                                                        \
    const size_t ko_ = (size_t)(TK) << 6;                                     \
    _Pragma("unroll") for (int c_ = 0; c_ < 4; ++c_)                          \
        stage16(Ag + (size_t)(c_ * 64) * lda + ko_,                           \
                &sA[P][c_ * 64 + wid * 8][0]);                                \
  } while (0)
#define STAGE_B(P, TK)                                                        \
  do {                                                                        \
    const size_t ko_ = (size_t)(TK) << 6;                                     \
    _Pragma("unroll") for (int c_ = 0; c_ < 4; ++c_)                          \
        stage16(Bg + (size_t)(c_ * 64) * ldb + ko_,                           \
                &sB[P][c_ * 64 + wid * 8][0]);                                \
  } while (0)

  bf16x8 afr[2][4][2], bfr[2][2][2];

#define READ_A(MH)                                                            \
  do {                                                                        \
    _Pragma("unroll") for (int mi_ = 0; mi_ < 4; ++mi_) {                     \
      const int arow_ = wr * 128 + (MH) * 64 + mi_ * 16 + l15;                \
      afr[MH][mi_][0] = *(const bf16x8*)(As0 + arow_ * 64 + swz0);            \
      afr[MH][mi_][1] = *(const bf16x8*)(As0 + arow_ * 64 + swz1);            \
    }                                                                         \
  } while (0)
#define READ_B(NH)                                                            \
  do {                                                                        \
    _Pragma("unroll") for (int ni_ = 0; ni_ < 2; ++ni_) {                     \
      const int brow_ = wc * 64 + (NH) * 32 + ni_ * 16 + l15;                 \
      bfr[NH][ni_][0] = *(const bf16x8*)(Bs0 + brow_ * 64 + swz0);            \
      bfr[NH][ni_][1] = *(const bf16x8*)(Bs0 + brow_ * 64 + swz1);            \
    }                                                                         \
  } while (0)
#define MFMA_QUAD(MH, NH)                                                     \
  do {                                                                        \
    __builtin_amdgcn_s_setprio(1);                                            \
    _Pragma("unroll") for (int mi_ = 0; mi_ < 4; ++mi_)                       \
        _Pragma("unroll") for (int ni_ = 0; ni_ < 2; ++ni_) {                 \
      acc[(MH)*4 + mi_][(NH)*2 + ni_] = __builtin_amdgcn_mfma_f32_16x16x32_bf16( \
          afr[MH][mi_][0], bfr[NH][ni_][0], acc[(MH)*4 + mi_][(NH)*2 + ni_], 0, 0, 0); \
      acc[(MH)*4 + mi_][(NH)*2 + ni_] = __builtin_amdgcn_mfma_f32_16x16x32_bf16( \
          afr[MH][mi_][1], bfr[NH][ni_][1], acc[(MH)*4 + mi_][(NH)*2 + ni_], 0, 0, 0); \
    }                                                                         \
    __builtin_amdgcn_s_setprio(0);                                            \
  } while (0)

  // prologue: tiles 0 and 1 fully staged (16 loads per wave)
  STAGE_A(0, 0);
  STAGE_B(0, 0);
  STAGE_A(1, 1);
  STAGE_B(1, 1);

  int p = 0;
  for (int t = 0; t < NT; ++t) {
    if (t == NT - 1) { WAITVM(0); } else { WAITVM(8); }  // tile t landed
    SBAR();                                   // all waves' tile-t loads landed
    const bf16* As0 = &sA[p][0][0];
    const bf16* Bs0 = &sB[p][0][0];
    // ---- P0 ----
    READ_A(0);
    READ_B(0);
    SBAR();
    MFMA_QUAD(0, 0);
    SBAR();
    // ---- P1 ----
    READ_A(1);
    READ_B(1);
    LGKM0();                                  // all my buf[p] reads complete
    __builtin_amdgcn_sched_barrier(0);
    SBAR();                                   // all waves' buf[p] reads done
    MFMA_QUAD(0, 1);
    SBAR();
    // ---- P2 ---- (safe: buf[p] fully read by every wave)
    if (t + 2 < NT) STAGE_A(p, t + 2);
    MFMA_QUAD(1, 0);
    SBAR();
    // ---- P3 ----
    if (t + 2 < NT) STAGE_B(p, t + 2);
    MFMA_QUAD(1, 1);
    p ^= 1;
    // loop-top SBAR doubles as P3-end barrier
  }

#undef STAGE_A
#undef STAGE_B
#undef READ_A
#undef READ_B
#undef MFMA_QUAD

#pragma unroll
  for (int nn = 0; nn < 4; ++nn) {
    const int n = n0 + wc * 64 + nn * 16 + l15;
    const float bv = bias[n];
#pragma unroll
    for (int mm = 0; mm < 8; ++mm) {
#pragma unroll
      for (int r = 0; r < 4; ++r) {
        const int m = m0 + wr * 128 + mm * 16 + quad * 4 + r;
        float v = acc[mm][nn][r] + bv;
        if (EPI == 1) v = gelu_tanh(v);
        C[(size_t)m * ldc + n] = (TO)v;
      }
    }
  }
}

// ---------------------------------------------------------------------------
// gate pre-activation GEMM: one gate per block (z = h*2+g), 128x128 tile,
// K = DH = 256. out[m, h*DHD + n] = sum_k xconv[m, h*DHD+k] * W[g][h][n][k]
// ---------------------------------------------------------------------------
__global__ __launch_bounds__(256) void gate_gemm(
    const bf16* __restrict__ xconv,
    const bf16* __restrict__ gxT, const bf16* __restrict__ gaT,
    bf16* __restrict__ gxr, bf16* __restrict__ gar) {
  const int h = blockIdx.z >> 1;
  const int g = blockIdx.z & 1;
  const bf16* A = xconv + h * DHD;                       // lda = DDIM
  const bf16* Bm = (g ? gaT : gxT) + (size_t)h * DHD * DHD;  // ldb = DHD
  bf16* C = (g ? gar : gxr) + h * DHD;                   // ldc = DDIM
  const int n0 = blockIdx.x * 128;
  const int m0 = blockIdx.y * 128;
  __shared__ bf16 As[128 * 32];
  __shared__ bf16 Bs[128 * 32];
  const int tid = threadIdx.x;
  const int lane = tid & 63;
  const int wid = tid >> 6;
  const int waveM = wid >> 1, waveN = wid & 1;
  const int quad = lane >> 4;
  const int l15 = lane & 15;
  const int srow = lane >> 2;
  const int scol = (lane & 3) * 8;

  f32x4 acc[4][4];
#pragma unroll
  for (int i = 0; i < 4; ++i)
#pragma unroll
    for (int j = 0; j < 4; ++j)
#pragma unroll
      for (int r = 0; r < 4; ++r) acc[i][j][r] = 0.f;

  for (int k0 = 0; k0 < DHD; k0 += 32) {
    if (k0) __syncthreads();
#pragma unroll
    for (int cc = 0; cc < 2; ++cc) {
      const int q = wid * 2 + cc;
      const int row = q * 16 + srow;
      stage16(A + (size_t)(m0 + row) * DDIM + k0 + scol, As + q * 512);
      stage16(Bm + (size_t)(n0 + row) * DHD + k0 + scol, Bs + q * 512);
    }
    __syncthreads();
    bf16x8 af[4], bfr[4];
#pragma unroll
    for (int i = 0; i < 4; ++i) {
      af[i]  = *(const bf16x8*)&As[(waveM * 64 + i * 16 + l15) * 32 + quad * 8];
      bfr[i] = *(const bf16x8*)&Bs[(waveN * 64 + i * 16 + l15) * 32 + quad * 8];
    }
#pragma unroll
    for (int i = 0; i < 4; ++i)
#pragma unroll
      for (int j = 0; j < 4; ++j)
        acc[i][j] = __builtin_amdgcn_mfma_f32_16x16x32_bf16(af[i], bfr[j], acc[i][j], 0, 0, 0);
  }

#pragma unroll
  for (int j = 0; j < 4; ++j) {
    const int n = n0 + waveN * 64 + j * 16 + l15;
#pragma unroll
    for (int i = 0; i < 4; ++i) {
#pragma unroll
      for (int r = 0; r < 4; ++r) {
        const int m = m0 + waveM * 64 + i * 16 + quad * 4 + r;
        C[(size_t)m * DDIM + n] = (bf16)acc[i][j][r];
      }
    }
  }
}

// ---------------------------------------------------------------------------
// depthwise causal conv, TW=4; bf16 data, fp32 weights
// ---------------------------------------------------------------------------
__global__ __launch_bounds__(256) void conv_kernel(
    const bf16* __restrict__ xp, const float* __restrict__ cw,
    const float* __restrict__ cb, const int* __restrict__ segp,
    bf16* __restrict__ xc) {
  int v = blockIdx.x * 256 + threadIdx.x;
  int dv = v & (DDIM / 8 - 1);
  int m = v >> 8;
  int d0 = dv * 8;
  int t = m & (TDIM - 1);
  int sp = segp[m];
  float acc[8];
#pragma unroll
  for (int j = 0; j < 8; ++j) acc[j] = cb[d0 + j];
#pragma unroll
  for (int i = 0; i < 4; ++i) {
    int shift = 3 - i;
    if (t >= shift && sp >= shift) {
      bf16x8 xv = *(const bf16x8*)&xp[(size_t)(m - shift) * DDIM + d0];
#pragma unroll
      for (int j = 0; j < 8; ++j) acc[j] = fmaf((float)xv[j], cw[i * DDIM + d0 + j], acc[j]);
    }
  }
  bf16x8 o;
#pragma unroll
  for (int j = 0; j < 8; ++j) o[j] = (bf16)acc[j];
  *(bf16x8*)&xc[(size_t)m * DDIM + d0] = o;
}

// ---------------------------------------------------------------------------
// transpose + convert gate weights: dst[h][j][i] = (bf16)src[h][i][j]
// ---------------------------------------------------------------------------
__global__ __launch_bounds__(256) void transpose_gates(
    const float* __restrict__ gxw, const float* __restrict__ gaw,
    bf16* __restrict__ gxT, bf16* __restrict__ gaT) {
  __shared__ bf16 tile[32][33];
  int zz = blockIdx.z;
  int h = zz >> 1;
  const float* src = (zz & 1) ? gaw : gxw;
  bf16* dst = (zz & 1) ? gaT : gxT;
  int j0 = blockIdx.x * 32;
  int i0 = blockIdx.y * 32;
  int r = threadIdx.x >> 5;
  int c = threadIdx.x & 31;
  for (int rr = r; rr < 32; rr += 8)
    tile[rr][c] = (bf16)src[(size_t)(h * DHD + i0 + rr) * DHD + j0 + c];
  __syncthreads();
  for (int rr = r; rr < 32; rr += 8)
    dst[(size_t)(h * DHD + j0 + rr) * DHD + i0 + c] = tile[c][rr];
}

// ---------------------------------------------------------------------------
// RG-LRU elementwise recompute, shared by scan phases
// ---------------------------------------------------------------------------
__device__ __forceinline__ void lru_elem(float pgx, float pga, float xc,
                                         float spv, bool reset,
                                         float& a, float& nr) {
  const float gx = sigmoid_f(pgx);
  const float ga = sigmoid_f(pga);
  const float la = -8.f * ga * spv;
  a = reset ? 0.f : __expf(la);
  const float mult = reset ? 1.f : sqrtf(fmaxf(1.f - __expf(2.f * la), 0.f));
  nr = xc * gx * mult;
}

// chunked scan phase 1: per (b, chunk, d) compute prod(a) and h across chunk
__global__ __launch_bounds__(256) void scan_phase1(
    const bf16* __restrict__ gxr, const bf16* __restrict__ gar,
    const bf16* __restrict__ xconv,
    const float* __restrict__ gxb, const float* __restrict__ gab,
    const float* __restrict__ apar, const int* __restrict__ segp,
    float* __restrict__ chA, float* __restrict__ chH) {
  int idx = blockIdx.x * 256 + threadIdx.x;
  int d = idx & (DDIM - 1);
  int c = (idx >> 11) & (NCHUNK - 1);
  int b = idx >> 17;
  const float gxbv = gxb[d], gabv = gab[d];
  const float spv = softplus_f(apar[d]);
  const int mrow = b * TDIM + c * LCHUNK;
  size_t base = (size_t)mrow * DDIM + d;
  float A = 1.f, hh = 0.f;
  for (int i = 0; i < LCHUNK; ++i) {
    size_t o = base + (size_t)i * DDIM;
    float a, nr;
    lru_elem((float)gxr[o] + gxbv, (float)gar[o] + gabv, (float)xconv[o],
             spv, segp[mrow + i] == 0, a, nr);
    hh = fmaf(a, hh, nr);
    A *= a;
  }
  int ci = (b * NCHUNK + c) * DDIM + d;
  chA[ci] = A;
  chH[ci] = hh;
}

__global__ __launch_bounds__(256) void scan_phase2(
    const float* __restrict__ chA, const float* __restrict__ chH,
    float* __restrict__ hst) {
  int idx = blockIdx.x * 256 + threadIdx.x;
  int d = idx & (DDIM - 1);
  int b = idx >> 11;
  float s = 0.f;
  for (int c = 0; c < NCHUNK; ++c) {
    int ci = (b * NCHUNK + c) * DDIM + d;
    hst[ci] = s;
    s = fmaf(chA[ci], s, chH[ci]);
  }
}

// phase 3: replay scan with chunk-start state; z = h*y in-place over y
__global__ __launch_bounds__(256) void scan_phase3(
    const bf16* __restrict__ gxr, const bf16* __restrict__ gar,
    const bf16* __restrict__ xconv,
    const float* __restrict__ gxb, const float* __restrict__ gab,
    const float* __restrict__ apar, const int* __restrict__ segp,
    const float* __restrict__ hst, bf16* __restrict__ yz) {
  int idx = blockIdx.x * 256 + threadIdx.x;
  int d = idx & (DDIM - 1);
  int c = (idx >> 11) & (NCHUNK - 1);
  int b = idx >> 17;
  const float gxbv = gxb[d], gabv = gab[d];
  const float spv = softplus_f(apar[d]);
  const int mrow = b * TDIM + c * LCHUNK;
  size_t base = (size_t)mrow * DDIM + d;
  float hh = hst[(b * NCHUNK + c) * DDIM + d];
  for (int i = 0; i < LCHUNK; ++i) {
    size_t o = base + (size_t)i * DDIM;
    float a, nr;
    lru_elem((float)gxr[o] + gxbv, (float)gar[o] + gabv, (float)xconv[o],
             spv, segp[mrow + i] == 0, a, nr);
    hh = fmaf(a, hh, nr);
    yz[o] = (bf16)(hh * (float)yz[o]);
  }
}

// ---------------------------------------------------------------------------
extern "C" void kernel_launch(void* const* d_in, const int* in_sizes, int n_in,
                              void* d_out, int out_size, void* d_ws, size_t ws_size,
                              hipStream_t stream) {
  const float* x    = (const float*)d_in[0];
  const int*   segp = (const int*)d_in[1];
  const float* Wy   = (const float*)d_in[2];
  const float* by   = (const float*)d_in[3];
  const float* Wx   = (const float*)d_in[4];
  const float* bx   = (const float*)d_in[5];
  const float* cw   = (const float*)d_in[6];
  const float* cb   = (const float*)d_in[7];
  const float* gxw  = (const float*)d_in[8];
  const float* gxb  = (const float*)d_in[9];
  const float* gaw  = (const float*)d_in[10];
  const float* gab  = (const float*)d_in[11];
  const float* apar = (const float*)d_in[12];
  const float* Wout = (const float*)d_in[13];
  const float* bout = (const float*)d_in[14];

  const size_t MD = (size_t)MTOT * DDIM;       // 16.78M elements
  const size_t WD = (size_t)DDIM * DDIM;       // 4.19M elements
  // d_out (fp32, 67 MB) as bf16 scratch until the final GEMM:
  bf16* xb    = (bf16*)d_out;                   // lower: xb -> xconv
  bf16* xproj = (bf16*)((char*)d_out + MD * 2); // upper: xproj -> gxr
  bf16* xconv = xb;
  bf16* gxr   = xproj;

  // ws (~92 MB): gar | W1 | WB1 | WB2 | gxT | gaT | chA | chH | hst
  char* ws = (char*)d_ws;
  bf16*  gar = (bf16*)ws;                        // 33.5 MB
  bf16*  W1  = (bf16*)(ws + MD * 2);             // y -> z (33.5 MB)
  bf16*  WB1 = (bf16*)(ws + 2 * MD * 2);         // Wxb, later Woutb (8.4 MB)
  bf16*  WB2 = (bf16*)(ws + 2 * MD * 2 + WD * 2);// Wyb (8.4 MB)
  char*  tail = ws + 2 * MD * 2 + 2 * WD * 2;
  const size_t GW = (size_t)HDIM * DHD * DHD * 2;      // 1 MiB
  const size_t CH = (size_t)BDIM * NCHUNK * DDIM * 4;  // 2 MiB
  bf16*  gxT = (bf16*)tail;
  bf16*  gaT = (bf16*)(tail + GW);
  float* chA = (float*)(tail + 2 * GW);
  float* chH = (float*)(tail + 2 * GW + CH);
  float* hst = (float*)(tail + 2 * GW + 2 * CH);

  dim3 blk(256);
  f2b<<<dim3(MD / 2048), blk, 0, stream>>>(x, xb);
  f2b<<<dim3(WD / 2048), blk, 0, stream>>>(Wx, WB1);
  f2b<<<dim3(WD / 2048), blk, 0, stream>>>(Wy, WB2);
  transpose_gates<<<dim3(8, 8, 16), blk, 0, stream>>>(gxw, gaw, gxT, gaT);

  // xproj = x @ Wx^T + bx ; y = gelu(x @ Wy^T + by)   (256^2, 4-phase pipe)
  gemm256<bf16, 0><<<dim3(8, 32), dim3(512), 0, stream>>>(xb, WB1, bx, xproj, DDIM, DDIM, DDIM, DDIM);
  gemm256<bf16, 1><<<dim3(8, 32), dim3(512), 0, stream>>>(xb, WB2, by, W1, DDIM, DDIM, DDIM, DDIM);

  // xconv in-place over xb (reads xproj; xb dead after the two GEMMs)
  conv_kernel<<<dim3(MTOT * (DDIM / 8) / 256), blk, 0, stream>>>(xproj, cw, cb, segp, xconv);

  // gate pre-activations: gxr over xproj (dead), gar in ws
  gate_gemm<<<dim3(2, 64, 16), blk, 0, stream>>>(xconv, gxT, gaT, gxr, gar);

  // chunked scan with fused RG-LRU elementwise; phase3 writes z = h*y over y
  scan_phase1<<<dim3(BDIM * NCHUNK * DDIM / 256), blk, 0, stream>>>(
      gxr, gar, xconv, gxb, gab, apar, segp, chA, chH);
  scan_phase2<<<dim3(BDIM * DDIM / 256), blk, 0, stream>>>(chA, chH, hst);
  scan_phase3<<<dim3(BDIM * NCHUNK * DDIM / 256), blk, 0, stream>>>(
      gxr, gar, xconv, gxb, gab, apar, segp, hst, W1);

  // out = z @ Wout^T + bout (fp32 over all of d_out; scratch dead)
  f2b<<<dim3(WD / 2048), blk, 0, stream>>>(Wout, WB1);
  gemm256<float, 0><<<dim3(8, 32), dim3(512), 0, stream>>>(W1, WB1, bout, (float*)d_out, DDIM, DDIM, DDIM, DDIM);
}